// Round 4
// baseline (244.166 us; speedup 1.0000x reference)
//
#include <hip/hip_runtime.h>

#define BB 32
#define IDF 64
#define QL 16384
#define CDF 768
#define SL 18
#define SLP 20             // padded row stride for sT rows
#define CLP 21             // odd stride for ctx_l -> conflict-free b32 reads
#define ADIM 100

// ---------------- Kernel A: sT[b,i,s] = sum_c wic[i,c] * ctx[b,c,s]; out init.
// grid = 512 (b = blk>>4, g = blk&15), block = 256 (4 waves, wave = row i).
__global__ __launch_bounds__(256, 2) void kA_source(
        const float* __restrict__ ctx,      // [B, CDF, SL]
        const float* __restrict__ wic,      // [IDF, CDF]
        const float* __restrict__ fc_b,     // [ADIM]
        float* __restrict__ sT,             // ws: [B, IDF, SLP]
        float* __restrict__ out)            // [B, ADIM]
{
    __shared__ float ctx_l[CDF * CLP];     // 64512 B
    const int blk  = blockIdx.x;
    const int tid  = threadIdx.x;
    const int wave = tid >> 6;
    const int lane = tid & 63;
    const int b = blk >> 4;
    const int g = blk & 15;

    // fused out-init (harness poisons out every launch); kB atomics add onto it
    if (blk < 13) {
        const int t = blk * 256 + tid;
        if (t < BB * ADIM) out[t] = fc_b[t % ADIM];
    }

    const float* ctxb = ctx + (size_t)b * CDF * SL;
    for (int t = tid; t < CDF * SL; t += 256) {
        const int c = t / SL;
        const int s = t - c * SL;
        ctx_l[c * CLP + s] = ctxb[t];
    }
    __syncthreads();

    const int i = g * 4 + wave;
    const float* wrow = wic + (size_t)i * CDF;

    float acc[SL];
#pragma unroll
    for (int s = 0; s < SL; s++) acc[s] = 0.f;

#pragma unroll 2
    for (int k = 0; k < CDF / 64; k++) {
        const int c = k * 64 + lane;
        const float wv = wrow[c];                    // coalesced 256 B/wave
#pragma unroll
        for (int s = 0; s < SL; s++) acc[s] += wv * ctx_l[c * CLP + s];  // odd stride: 2-way max
    }
#pragma unroll
    for (int s = 0; s < SL; s++) {
        float a = acc[s];
#pragma unroll
        for (int off = 32; off; off >>= 1) a += __shfl_xor(a, off, 64);
        if (lane == 0) sT[((size_t)b * IDF + i) * SLP + s] = a;
    }
}

// ---------------- Kernel B: scores -> softmax -> dot(v) -> wq (LDS) -> fc dot -> out.
// grid = (32 qt, 32 b), block 256. REWRITE: inp has ZERO cross-thread reuse, so
// the LDS/DMA staging is deleted. Each thread owns q = {2*tid, 2*tid+1} via
// float2 loads (512 B/wave coalesced), software-pipelined 2 groups (16 loads,
// 32 KB/block) ahead with a static ping-pong. No barriers in the main loop:
// compiler emits counted vmcnt per use instead of full drains.
__global__ __launch_bounds__(256, 4) void kB_attn(
        const float* __restrict__ inp,     // [B, IDF, QL]
        const float* __restrict__ sT,      // ws: [B, IDF, SLP]
        const float* __restrict__ conv_w,  // [IDF]
        const float* __restrict__ conv_b,  // [1]
        const float* __restrict__ fcw,     // [ADIM, QL]
        float* __restrict__ out)           // [B, ADIM]
{
    __shared__ float v_l[SL];
    __shared__ __align__(16) float wq_l[512];         // fused-kC staging
    const int b   = blockIdx.y;
    const int qt  = blockIdx.x;
    const int tid = threadIdx.x;
    const int wave = tid >> 6;
    const int lane = tid & 63;
    const float* st = sT + (size_t)b * IDF * SLP;

    if (tid < SL) {                         // one-time: v[s] = sum_i cw[i]*st[i][s]
        float a = 0.f;
        for (int i = 0; i < IDF; i++) a += conv_w[i] * st[i * SLP + tid];
        v_l[tid] = a;                       // visibility ordered by syncthreads below
    }

    // thread's two queries: q0 = qt*512 + 2*tid, q1 = q0+1 (float2, 8B aligned)
    const float* gq = inp + (size_t)b * IDF * QL + (size_t)qt * 512 + 2 * tid;

    float2 sc[SL];
#pragma unroll
    for (int s = 0; s < SL; s++) sc[s] = make_float2(0.f, 0.f);

    float2 xa[8], xb[8];

#define LOADG(dst, base_i)                                                   \
    _Pragma("unroll")                                                        \
    for (int r_ = 0; r_ < 8; r_++)                                           \
        dst[r_] = *(const float2*)(gq + (size_t)((base_i) + r_) * QL);

#define FMAG(src, base_i)                                                    \
    _Pragma("unroll")                                                        \
    for (int r_ = 0; r_ < 8; r_++) {                                         \
        const float* strow_ = st + ((base_i) + r_) * SLP;  /* uniform */     \
        _Pragma("unroll")                                                    \
        for (int s_ = 0; s_ < SL; s_++) {                                    \
            const float rs_ = strow_[s_];                                    \
            sc[s_].x += src[r_].x * rs_;                                     \
            sc[s_].y += src[r_].y * rs_;                                     \
        }                                                                    \
    }

    LOADG(xa, 0)
    LOADG(xb, 8)          // 2 groups (32 KB/block) in flight
    FMAG(xa, 0)  LOADG(xa, 16)
    FMAG(xb, 8)  LOADG(xb, 24)
    FMAG(xa, 16) LOADG(xa, 32)
    FMAG(xb, 24) LOADG(xb, 40)
    FMAG(xa, 32) LOADG(xa, 48)
    FMAG(xb, 40) LOADG(xb, 56)
    FMAG(xa, 48)
    FMAG(xb, 56)
#undef LOADG
#undef FMAG

    __syncthreads();       // v_l ready (wave 0 wrote it); no other main-loop barriers

    float2 m = sc[0];
#pragma unroll
    for (int s = 1; s < SL; s++) {
        m.x = fmaxf(m.x, sc[s].x);
        m.y = fmaxf(m.y, sc[s].y);
    }
    float2 l = make_float2(0.f, 0.f);
    float2 o = make_float2(0.f, 0.f);
#pragma unroll
    for (int s = 0; s < SL; s++) {
        const float vs = v_l[s];
        float2 p;
        p.x = __expf(sc[s].x - m.x);
        p.y = __expf(sc[s].y - m.y);
        l.x += p.x; l.y += p.y;
        o.x += p.x * vs; o.y += p.y * vs;
    }
    const float cb = conv_b[0];
    wq_l[2 * tid]     = o.x / l.x + cb;
    wq_l[2 * tid + 1] = o.y / l.y + cb;
    __syncthreads();

    // ---- fused kC: out[b,a] += dot(fcw[a, qt*512 : qt*512+512], wq_l)
    // wave w handles a = 4*j + w (25 rows). Loads coalesced: lane*16 B.
    const float4 w0 = *(const float4*)(&wq_l[lane * 4]);        // hoisted, loop-invariant
    const float4 w1 = *(const float4*)(&wq_l[256 + lane * 4]);
    const float* fbase = fcw + (size_t)qt * 512 + lane * 4;
#pragma unroll 2
    for (int j = 0; j < 25; j++) {
        const int a = j * 4 + wave;
        const float4 f0 = *(const float4*)(fbase + (size_t)a * QL);
        const float4 f1 = *(const float4*)(fbase + (size_t)a * QL + 256);
        float r = f0.x * w0.x + f0.y * w0.y + f0.z * w0.z + f0.w * w0.w
                + f1.x * w1.x + f1.y * w1.y + f1.z * w1.z + f1.w * w1.w;
#pragma unroll
        for (int off = 32; off; off >>= 1) r += __shfl_xor(r, off, 64);
        if (lane == 0) atomicAdd(&out[b * ADIM + a], r);
    }
}

extern "C" void kernel_launch(void* const* d_in, const int* in_sizes, int n_in,
                              void* d_out, int out_size, void* d_ws, size_t ws_size,
                              hipStream_t stream)
{
    const float* inputs     = (const float*)d_in[0];  // [32,64,128,128]
    const float* context    = (const float*)d_in[1];  // [32,768,18]
    const float* conv_ctx_w = (const float*)d_in[2];  // [64,768]
    const float* conv_w     = (const float*)d_in[3];  // [64]
    const float* conv_b     = (const float*)d_in[4];  // [1]
    const float* fc_w       = (const float*)d_in[5];  // [100,16384]
    const float* fc_b       = (const float*)d_in[6];  // [100]
    float* out = (float*)d_out;

    float* ws = (float*)d_ws;
    float* sT = ws;                                   // 32*64*20 = 40960 floats

    kA_source<<<dim3(512), dim3(256), 0, stream>>>(context, conv_ctx_w, fc_b, sT, out);
    kB_attn<<<dim3(32, BB), dim3(256), 0, stream>>>(inputs, sT, conv_w, conv_b, fc_w, out);
}

// Round 5
// 239.459 us; speedup vs baseline: 1.0197x; 1.0197x over previous
//
#include <hip/hip_runtime.h>

#define BB 32
#define IDF 64
#define QL 16384
#define CDF 768
#define SL 18
#define SLP 20             // padded row stride for sT rows
#define CLP 21             // odd stride for ctx_l -> conflict-free b32 reads
#define ADIM 100

// ---------------- Kernel A: sT[b,i,s] = sum_c wic[i,c] * ctx[b,c,s]; out init.
// grid = 512 (b = blk>>4, g = blk&15), block = 256 (4 waves, wave = row i).
__global__ __launch_bounds__(256, 2) void kA_source(
        const float* __restrict__ ctx,      // [B, CDF, SL]
        const float* __restrict__ wic,      // [IDF, CDF]
        const float* __restrict__ fc_b,     // [ADIM]
        float* __restrict__ sT,             // ws: [B, IDF, SLP]
        float* __restrict__ out)            // [B, ADIM]
{
    __shared__ float ctx_l[CDF * CLP];     // 64512 B
    const int blk  = blockIdx.x;
    const int tid  = threadIdx.x;
    const int wave = tid >> 6;
    const int lane = tid & 63;
    const int b = blk >> 4;
    const int g = blk & 15;

    // fused out-init (harness poisons out every launch); kB atomics add onto it
    if (blk < 13) {
        const int t = blk * 256 + tid;
        if (t < BB * ADIM) out[t] = fc_b[t % ADIM];
    }

    const float* ctxb = ctx + (size_t)b * CDF * SL;
    for (int t = tid; t < CDF * SL; t += 256) {
        const int c = t / SL;
        const int s = t - c * SL;
        ctx_l[c * CLP + s] = ctxb[t];
    }
    __syncthreads();

    const int i = g * 4 + wave;
    const float* wrow = wic + (size_t)i * CDF;

    float acc[SL];
#pragma unroll
    for (int s = 0; s < SL; s++) acc[s] = 0.f;

#pragma unroll 2
    for (int k = 0; k < CDF / 64; k++) {
        const int c = k * 64 + lane;
        const float wv = wrow[c];                    // coalesced 256 B/wave
#pragma unroll
        for (int s = 0; s < SL; s++) acc[s] += wv * ctx_l[c * CLP + s];  // odd stride: 2-way max
    }
#pragma unroll
    for (int s = 0; s < SL; s++) {
        float a = acc[s];
#pragma unroll
        for (int off = 32; off; off >>= 1) a += __shfl_xor(a, off, 64);
        if (lane == 0) sT[((size_t)b * IDF + i) * SLP + s] = a;
    }
}

// ---------------- Kernel B: scores -> softmax -> dot(v) -> wq (LDS) -> fc dot -> out.
// grid = (32 qt, 32 b), block 256. x path: register ping-pong of float2 global
// loads (vmcnt-counted, no main-loop barriers). NEW: st block staged to LDS once
// (5 KB) and read via broadcast ds_read_b128 (lgkm pipe) — removes 1152 per-thread
// global L2 loads that were serializing the loop through vmcnt waits.
__global__ __launch_bounds__(256, 4) void kB_attn(
        const float* __restrict__ inp,     // [B, IDF, QL]
        const float* __restrict__ sT,      // ws: [B, IDF, SLP]
        const float* __restrict__ conv_w,  // [IDF]
        const float* __restrict__ conv_b,  // [1]
        const float* __restrict__ fcw,     // [ADIM, QL]
        float* __restrict__ out)           // [B, ADIM]
{
    __shared__ __align__(16) float st_l[IDF * SLP];   // 5120 B, row stride 80 B (16B-aligned)
    __shared__ float v_l[SL];
    __shared__ __align__(16) float wq_l[512];         // fused-kC staging
    const int b   = blockIdx.y;
    const int qt  = blockIdx.x;
    const int tid = threadIdx.x;
    const int wave = tid >> 6;
    const int lane = tid & 63;

    // stage st block (incl. pad slots) into LDS: 1280 floats, coalesced
    {
        const float* stg = sT + (size_t)b * IDF * SLP;
#pragma unroll
        for (int t = tid; t < IDF * SLP; t += 256) st_l[t] = stg[t];
    }
    __syncthreads();

    if (tid < SL) {                         // one-time: v[s] = sum_i cw[i]*st[i][s]
        float a = 0.f;
        for (int i = 0; i < IDF; i++) a += conv_w[i] * st_l[i * SLP + tid];
        v_l[tid] = a;                       // read after the pre-tail barrier
    }

    // thread's two queries: q0 = qt*512 + 2*tid, q1 = q0+1 (float2, 8B aligned)
    const float* gq = inp + (size_t)b * IDF * QL + (size_t)qt * 512 + 2 * tid;

    float2 sc[SL];
#pragma unroll
    for (int s = 0; s < SL; s++) sc[s] = make_float2(0.f, 0.f);

    float2 xa[8], xb[8];

#define LOADG(dst, base_i)                                                   \
    _Pragma("unroll")                                                        \
    for (int r_ = 0; r_ < 8; r_++)                                           \
        dst[r_] = *(const float2*)(gq + (size_t)((base_i) + r_) * QL);

    // st row from LDS: broadcast reads (same addr all lanes), b128/b64 — lgkm pipe
#define FMAG(src, base_i)                                                    \
    _Pragma("unroll")                                                        \
    for (int r_ = 0; r_ < 8; r_++) {                                         \
        const float* row_ = &st_l[((base_i) + r_) * SLP];                    \
        const float4 t0_ = *(const float4*)(row_ + 0);                       \
        const float4 t1_ = *(const float4*)(row_ + 4);                       \
        const float4 t2_ = *(const float4*)(row_ + 8);                       \
        const float4 t3_ = *(const float4*)(row_ + 12);                      \
        const float2 t4_ = *(const float2*)(row_ + 16);                      \
        const float rsv_[SL] = {t0_.x, t0_.y, t0_.z, t0_.w,                  \
                                t1_.x, t1_.y, t1_.z, t1_.w,                  \
                                t2_.x, t2_.y, t2_.z, t2_.w,                  \
                                t3_.x, t3_.y, t3_.z, t3_.w,                  \
                                t4_.x, t4_.y};                               \
        _Pragma("unroll")                                                    \
        for (int s_ = 0; s_ < SL; s_++) {                                    \
            sc[s_].x += src[r_].x * rsv_[s_];                                \
            sc[s_].y += src[r_].y * rsv_[s_];                                \
        }                                                                    \
    }

    LOADG(xa, 0)
    LOADG(xb, 8)          // 2 groups (32 KB/block) in flight
    FMAG(xa, 0)  LOADG(xa, 16)
    FMAG(xb, 8)  LOADG(xb, 24)
    FMAG(xa, 16) LOADG(xa, 32)
    FMAG(xb, 24) LOADG(xb, 40)
    FMAG(xa, 32) LOADG(xa, 48)
    FMAG(xb, 40) LOADG(xb, 56)
    FMAG(xa, 48)
    FMAG(xb, 56)
#undef LOADG
#undef FMAG

    __syncthreads();       // v_l ready; wq_l reuse guarded below

    float2 m = sc[0];
#pragma unroll
    for (int s = 1; s < SL; s++) {
        m.x = fmaxf(m.x, sc[s].x);
        m.y = fmaxf(m.y, sc[s].y);
    }
    float2 l = make_float2(0.f, 0.f);
    float2 o = make_float2(0.f, 0.f);
#pragma unroll
    for (int s = 0; s < SL; s++) {
        const float vs = v_l[s];
        float2 p;
        p.x = __expf(sc[s].x - m.x);
        p.y = __expf(sc[s].y - m.y);
        l.x += p.x; l.y += p.y;
        o.x += p.x * vs; o.y += p.y * vs;
    }
    const float cb = conv_b[0];
    wq_l[2 * tid]     = o.x / l.x + cb;
    wq_l[2 * tid + 1] = o.y / l.y + cb;
    __syncthreads();

    // ---- fused kC: out[b,a] += dot(fcw[a, qt*512 : qt*512+512], wq_l)
    // wave w handles a = 4*j + w (25 rows). Loads coalesced: lane*16 B.
    const float4 w0 = *(const float4*)(&wq_l[lane * 4]);        // hoisted, loop-invariant
    const float4 w1 = *(const float4*)(&wq_l[256 + lane * 4]);
    const float* fbase = fcw + (size_t)qt * 512 + lane * 4;
#pragma unroll 2
    for (int j = 0; j < 25; j++) {
        const int a = j * 4 + wave;
        const float4 f0 = *(const float4*)(fbase + (size_t)a * QL);
        const float4 f1 = *(const float4*)(fbase + (size_t)a * QL + 256);
        float r = f0.x * w0.x + f0.y * w0.y + f0.z * w0.z + f0.w * w0.w
                + f1.x * w1.x + f1.y * w1.y + f1.z * w1.z + f1.w * w1.w;
#pragma unroll
        for (int off = 32; off; off >>= 1) r += __shfl_xor(r, off, 64);
        if (lane == 0) atomicAdd(&out[b * ADIM + a], r);
    }
}

extern "C" void kernel_launch(void* const* d_in, const int* in_sizes, int n_in,
                              void* d_out, int out_size, void* d_ws, size_t ws_size,
                              hipStream_t stream)
{
    const float* inputs     = (const float*)d_in[0];  // [32,64,128,128]
    const float* context    = (const float*)d_in[1];  // [32,768,18]
    const float* conv_ctx_w = (const float*)d_in[2];  // [64,768]
    const float* conv_w     = (const float*)d_in[3];  // [64]
    const float* conv_b     = (const float*)d_in[4];  // [1]
    const float* fc_w       = (const float*)d_in[5];  // [100,16384]
    const float* fc_b       = (const float*)d_in[6];  // [100]
    float* out = (float*)d_out;

    float* ws = (float*)d_ws;
    float* sT = ws;                                   // 32*64*20 = 40960 floats

    kA_source<<<dim3(512), dim3(256), 0, stream>>>(context, conv_ctx_w, fc_b, sT, out);
    kB_attn<<<dim3(32, BB), dim3(256), 0, stream>>>(inputs, sT, conv_w, conv_b, fc_w, out);
}